// Round 18
// baseline (151.169 us; speedup 1.0000x reference)
//
#include <hip/hip_runtime.h>
#include <math.h>

#define QR_M 512
#define QR_N 26
#define OUTC 512
#define LDP 30   // small-matrix LDS row stride (floats)

using half8_t = __attribute__((ext_vector_type(8))) _Float16;
using f32x4   = __attribute__((ext_vector_type(4))) float;

// ---------------------------------------------------------------------------
// K0 (R12/R15-proven): partial Gram. Block b sums rows 32b..32b+31 of
// A = w+1e-8 into gp[b][351] (upper-tri pairs). 16 blocks in parallel.
// ---------------------------------------------------------------------------
__global__ __launch_bounds__(448) void gram_part(const float* __restrict__ w,
                                                 float* __restrict__ gp) {
  __shared__ float Ab[32][27];
  const int tid = threadIdx.x;
  const int b   = blockIdx.x;
  if (tid < 416) {
    const int r  = tid / 13;
    const int c2 = tid - r * 13;
    const float2 v = *reinterpret_cast<const float2*>(
        w + (size_t)(b * 32 + r) * QR_N + 2 * c2);
    Ab[r][2 * c2]     = v.x + 1e-8f;
    Ab[r][2 * c2 + 1] = v.y + 1e-8f;
  }
  __syncthreads();
  if (tid < 351) {
    int cb = 0, rem = tid;
    while (rem >= QR_N - cb) { rem -= QR_N - cb; ++cb; }
    const int d = cb + rem;
    float s = 0.0f;
#pragma unroll
    for (int r = 0; r < 32; ++r) s += Ab[r][cb] * Ab[r][d];
    gp[b * 351 + tid] = s;
  }
}

// ---------------------------------------------------------------------------
// Fused kernel (R17 structure, combine-coverage FIXED): per-block redundant
// QR prologue (deterministic -> bit-identical Q across blocks), then the
// R16-proven streaming MFMA matmul with nt stores, hot loop byte-identical.
// R17's NaN: `if (tid < 351)` combine in a 256-thread block left Gs entries
// 256..350 uninitialized -> sqrt(negative) -> NaN. Now a strided loop.
// LDS UNION: Gs+Rt+Qs [39.2 KB, prologue] overlap tile [33.8 KB, main]
// -> 4 blocks/CU preserved.
// ---------------------------------------------------------------------------
#define SM_GS   0                        // float [26][30]  = 3120 B
#define SM_RT   3200                     // float [26][30]  = 3120 B
#define SM_QS   6400                     // f16  [512][32]  = 32768 B
#define SM_SIZE 39168                    // max(39168, tile 33792)

__global__ __launch_bounds__(256, 4) void fused_dir(const float* __restrict__ w,
                                                    const float* __restrict__ gp,
                                                    const float* __restrict__ x,
                                                    float* __restrict__ out,
                                                    int nblk32) {
  __shared__ __align__(16) char smem[SM_SIZE];
  float*    Gs   = reinterpret_cast<float*>(smem + SM_GS);     // [26][30]
  float*    Rt   = reinterpret_cast<float*>(smem + SM_RT);     // [26][30]
  _Float16* Qs   = reinterpret_cast<_Float16*>(smem + SM_QS);  // [512][32]
  float*    tile = reinterpret_cast<float*>(smem);             // [4][16*132]

  const int tid = threadIdx.x;
  const int l   = tid & 63;
  const int wid = tid >> 6;

  // ---- issue own-row loads early (rows tid, tid+256) ----
  float y0[QR_N], y1[QR_N];
  {
    const float2* w0 = reinterpret_cast<const float2*>(w + (size_t)tid * QR_N);
    const float2* w1 = reinterpret_cast<const float2*>(w + (size_t)(tid + 256) * QR_N);
#pragma unroll
    for (int i = 0; i < 13; ++i) {
      const float2 v0 = w0[i], v1 = w1[i];
      y0[2 * i] = v0.x + 1e-8f; y0[2 * i + 1] = v0.y + 1e-8f;
      y1[2 * i] = v1.x + 1e-8f; y1[2 * i + 1] = v1.y + 1e-8f;
    }
  }

  // ---- combine Gram partials -> Gs (ALL 351 entries; 256-thr strided) ----
#pragma unroll
  for (int p = tid; p < 351; p += 256) {
    float acc = 0.0f;
#pragma unroll
    for (int b = 0; b < 16; ++b) acc += gp[b * 351 + p];
    int cb = 0, rem = p;
    while (rem >= QR_N - cb) { rem -= QR_N - cb; ++cb; }
    const int d = cb + rem;
    Gs[cb * LDP + d] = acc;
    Gs[d * LDP + cb] = acc;
  }
  __syncthreads();

  // ---- recursion: wave 0, registers + shfl (R10-proven) ----
  if (wid == 0) {
    const int c  = l;
    const int cm = (c < QR_N) ? c : (QR_N - 1);
    float gcol[QR_N], tcol[QR_N], rcol[QR_N];
#pragma unroll
    for (int r = 0; r < QR_N; ++r) gcol[r] = Gs[r * LDP + cm];
#pragma unroll
    for (int r = 0; r < QR_N; ++r) tcol[r] = w[r * QR_N + cm] + 1e-8f;
#pragma unroll
    for (int r = 0; r < QR_N; ++r) rcol[r] = 0.0f;

#pragma unroll
    for (int j = 0; j < QR_N; ++j) {
      float tg = gcol[j];
#pragma unroll
      for (int r = 0; r < QR_N; ++r) {
        if (r < j) tg -= __shfl(rcol[r], j) * rcol[r];
      }
      const float nsq   = __shfl(tg, j);
      const float alpha = __shfl(tcol[j], j);
      const float norm  = sqrtf(nsq);
      const float beta  = (alpha >= 0.0f) ? -norm : norm;  // -sign(alpha)*norm
      const float tau   = (beta - alpha) / beta;
      const float scale = 1.0f / (alpha - beta);
      const float wc    = (tg - beta * tcol[j]) * scale;
      const float tw    = (c > j) ? (tau * wc) : 0.0f;
      tcol[j] -= tw;
      rcol[j]  = (c == j) ? beta : tcol[j];
#pragma unroll
      for (int rr = 0; rr < QR_N; ++rr) {
        if (rr > j) {
          const float vtop = __shfl(tcol[rr], j) * scale;
          tcol[rr] -= tw * vtop;
        }
      }
      if (c >= j && c < QR_N) Rt[c * LDP + j] = rcol[j];  // write-only LDS
    }
  }
  __syncthreads();

  // ---- solve 2 rows/thread -> Qs (f16, k-padded) ----
  {
    float rinv[QR_N];
#pragma unroll
    for (int cc = 0; cc < QR_N; ++cc) rinv[cc] = 1.0f / Rt[cc * LDP + cc];

#pragma unroll
    for (int cc = 0; cc < QR_N; ++cc) {
      float s0 = y0[cc], s1 = y1[cc];
      int k = 0;
#pragma unroll
      for (; k + 1 < cc; k += 2) {
        const float2 rk = *reinterpret_cast<const float2*>(&Rt[cc * LDP + k]);
        s0 -= y0[k] * rk.x + y0[k + 1] * rk.y;
        s1 -= y1[k] * rk.x + y1[k + 1] * rk.y;
      }
      if (k < cc) { const float rk = Rt[cc * LDP + k]; s0 -= y0[k] * rk; s1 -= y1[k] * rk; }
      y0[cc] = s0 * rinv[cc];
      y1[cc] = s1 * rinv[cc];
    }

    half8_t h[4];
#pragma unroll
    for (int e = 0; e < 8; ++e) h[0][e] = (_Float16)y0[e];
#pragma unroll
    for (int e = 0; e < 8; ++e) h[1][e] = (_Float16)y0[8 + e];
#pragma unroll
    for (int e = 0; e < 8; ++e) h[2][e] = (_Float16)y0[16 + e];
    h[3][0] = (_Float16)y0[24]; h[3][1] = (_Float16)y0[25];
#pragma unroll
    for (int e = 2; e < 8; ++e) h[3][e] = (_Float16)0.0f;
    half8_t* q0 = reinterpret_cast<half8_t*>(Qs + (size_t)tid * 32);
    q0[0] = h[0]; q0[1] = h[1]; q0[2] = h[2]; q0[3] = h[3];

#pragma unroll
    for (int e = 0; e < 8; ++e) h[0][e] = (_Float16)y1[e];
#pragma unroll
    for (int e = 0; e < 8; ++e) h[1][e] = (_Float16)y1[8 + e];
#pragma unroll
    for (int e = 0; e < 8; ++e) h[2][e] = (_Float16)y1[16 + e];
    h[3][0] = (_Float16)y1[24]; h[3][1] = (_Float16)y1[25];
#pragma unroll
    for (int e = 2; e < 8; ++e) h[3][e] = (_Float16)0.0f;
    half8_t* q1 = reinterpret_cast<half8_t*>(Qs + (size_t)(tid + 256) * 32);
    q1[0] = h[0]; q1[1] = h[1]; q1[2] = h[2]; q1[3] = h[3];
  }
  __syncthreads();

  // ---- bq preload from Qs, then release the union for `tile` ----
  const int rloc  = l & 15;
  const int grp   = l >> 4;
  const int k0    = grp * 8;
  const int rhalf = (wid >> 1) * 16;
  const int chalf = (wid & 1) * 256;
  const int t2b   = (wid & 1) * 16;

  half8_t bq[16];
#pragma unroll
  for (int t2 = 0; t2 < 16; ++t2)
    bq[t2] = *reinterpret_cast<const half8_t*>(Qs + (size_t)((t2b + t2) * 16 + rloc) * 32 + k0);
  __syncthreads();   // all Qs reads done before tile overwrites the union

  float* tw = tile + wid * (16 * 132);

  // ---- main loop: R16-proven hot loop (MFMA + LDS epilogue + nt stores) ----
  for (int rb = blockIdx.x; rb < nblk32; rb += gridDim.x) {
    const int row = rb * 32 + rhalf + rloc;
    half8_t av;
    const float* xp = x + (size_t)row * QR_N + k0;
    if (grp < 3) {
#pragma unroll
      for (int e = 0; e < 4; ++e) {
        float2 v = *reinterpret_cast<const float2*>(xp + 2 * e);
        av[2 * e]     = (_Float16)v.x;
        av[2 * e + 1] = (_Float16)v.y;
      }
    } else {
      float2 v = *reinterpret_cast<const float2*>(xp);
      av[0] = (_Float16)v.x; av[1] = (_Float16)v.y;
#pragma unroll
      for (int e = 2; e < 8; ++e) av[e] = (_Float16)0.0f;
    }

#pragma unroll
    for (int cc = 0; cc < 2; ++cc) {
#pragma unroll
      for (int tt = 0; tt < 8; ++tt) {
        f32x4 acc = {0.0f, 0.0f, 0.0f, 0.0f};
        acc = __builtin_amdgcn_mfma_f32_16x16x32_f16(av, bq[cc * 8 + tt], acc, 0, 0, 0);
#pragma unroll
        for (int j = 0; j < 4; ++j)
          tw[(grp * 4 + j) * 132 + tt * 16 + rloc] = acc[j];
      }
      __syncthreads();
#pragma unroll
      for (int it = 0; it < 8; ++it) {
        const int r  = it * 2 + (l >> 5);
        const int cg = l & 31;
        f32x4 v = *reinterpret_cast<const f32x4*>(&tw[r * 132 + 4 * cg]);
        __builtin_nontemporal_store(
            v, reinterpret_cast<f32x4*>(
                   out + (size_t)(rb * 32 + rhalf + r) * OUTC + chalf + cc * 128 + 4 * cg));
      }
      __syncthreads();
    }
  }
}

extern "C" void kernel_launch(void* const* d_in, const int* in_sizes, int n_in,
                              void* d_out, int out_size, void* d_ws, size_t ws_size,
                              hipStream_t stream) {
  const float* input  = (const float*)d_in[0];   // [B, 26] f32
  const float* weight = (const float*)d_in[1];   // [512, 26] f32
  float* out = (float*)d_out;                    // [B, 512] f32
  float* gp  = (float*)d_ws;                     // 16*351 f32 = 22.5 KB

  const int B = in_sizes[0] / QR_N;              // 262144
  const int nblk32 = B / 32;                     // 8192

  gram_part<<<16, 448, 0, stream>>>(weight, gp);
  fused_dir<<<1024, 256, 0, stream>>>(weight, gp, input, out, nblk32);
}

// Round 19
// 122.652 us; speedup vs baseline: 1.2325x; 1.2325x over previous
//
#include <hip/hip_runtime.h>
#include <math.h>

// Round-19: byte-identical restore of the R16 optimum (122.8 us measured).
// R18 post-mortem: fusion pays the serial recursion wall per-block and can
// only save ~2 launch gaps -> structurally negative (3 attempts: +9..+28 us).

#define QR_M 512
#define QR_N 26
#define OUTC 512
#define LDP 30   // LDS row stride (floats): even (8B-aligned float2)

using half8_t = __attribute__((ext_vector_type(8))) _Float16;
using f32x4   = __attribute__((ext_vector_type(4))) float;

// ---------------------------------------------------------------------------
// Kernel 1 (R10-proven): Gram-domain Householder QR.
// Ph1 stage A; Ph2 Gram via 2x2-blocked partials; Ph3 26-step recursion on
// wave 0 in registers+shfl (LAPACK slarfg signs); Ph4 per-row forward-
// substitution solve -> Q as f16 [512][32], k-padded. ~18 us exec.
// ---------------------------------------------------------------------------
__global__ __launch_bounds__(512) void qr_kernel(const float* __restrict__ w,
                                                 _Float16* __restrict__ qf) {
  const int tid  = threadIdx.x;
  const int lane = tid & 63;
  const int wid  = tid >> 6;

  __shared__ float As[QR_M][LDP];
  __shared__ float Gs[QR_N][LDP];
  __shared__ float Rt[QR_N][LDP];
  __shared__ float Gp[4][91][4];

  // ---- Phase 1: stage A ----
  {
    const float2* wp = reinterpret_cast<const float2*>(w + (size_t)tid * QR_N);
    float2 v[13];
#pragma unroll
    for (int i = 0; i < 13; ++i) v[i] = wp[i];
#pragma unroll
    for (int i = 0; i < 13; ++i) {
      As[tid][2 * i]     = v[i].x + 1e-8f;
      As[tid][2 * i + 1] = v[i].y + 1e-8f;
    }
  }
  __syncthreads();

  // ---- Phase 2a: partial Gram (364 threads) ----
  if (tid < 364) {
    const int chunk = tid / 91;
    const int blk   = tid - chunk * 91;
    int cb = 0, rem = blk;
    while (rem >= 13 - cb) { rem -= 13 - cb; ++cb; }
    const int db = cb + rem;
    const int c0 = 2 * cb, d0 = 2 * db;
    float s00 = 0.f, s01 = 0.f, s10 = 0.f, s11 = 0.f;
    const int r0 = chunk * 128;
    for (int r = r0; r < r0 + 128; ++r) {
      const float2 ac = *reinterpret_cast<const float2*>(&As[r][c0]);
      const float2 ad = *reinterpret_cast<const float2*>(&As[r][d0]);
      s00 += ac.x * ad.x; s01 += ac.x * ad.y;
      s10 += ac.y * ad.x; s11 += ac.y * ad.y;
    }
    Gp[chunk][blk][0] = s00; Gp[chunk][blk][1] = s01;
    Gp[chunk][blk][2] = s10; Gp[chunk][blk][3] = s11;
  }
  __syncthreads();

  // ---- Phase 2b: combine partials -> Gs ----
  if (tid < 364) {
    const int blk = tid >> 2;
    const int v   = tid & 3;
    int cb = 0, rem = blk;
    while (rem >= 13 - cb) { rem -= 13 - cb; ++cb; }
    const int db = cb + rem;
    const float s = Gp[0][blk][v] + Gp[1][blk][v] + Gp[2][blk][v] + Gp[3][blk][v];
    const int c = 2 * cb + (v >> 1);
    const int d = 2 * db + (v & 1);
    Gs[c][d] = s;
    Gs[d][c] = s;
  }
  __syncthreads();

  // ---- Phase 3: 26-step recursion, wave 0, registers + shfl ----
  if (wid == 0) {
    const int c  = lane;
    const int cm = (c < QR_N) ? c : (QR_N - 1);
    float gcol[QR_N], tcol[QR_N], rcol[QR_N];
#pragma unroll
    for (int r = 0; r < QR_N; ++r) gcol[r] = Gs[r][cm];
#pragma unroll
    for (int r = 0; r < QR_N; ++r) tcol[r] = As[r][cm];
#pragma unroll
    for (int r = 0; r < QR_N; ++r) rcol[r] = 0.0f;

#pragma unroll
    for (int j = 0; j < QR_N; ++j) {
      float tg = gcol[j];
#pragma unroll
      for (int r = 0; r < QR_N; ++r) {
        if (r < j) tg -= __shfl(rcol[r], j) * rcol[r];
      }
      const float nsq   = __shfl(tg, j);
      const float alpha = __shfl(tcol[j], j);
      const float norm  = sqrtf(nsq);
      const float beta  = (alpha >= 0.0f) ? -norm : norm;  // -sign(alpha)*norm
      const float tau   = (beta - alpha) / beta;
      const float scale = 1.0f / (alpha - beta);
      const float wc    = (tg - beta * tcol[j]) * scale;
      const float tw    = (c > j) ? (tau * wc) : 0.0f;
      tcol[j] -= tw;
      rcol[j]  = (c == j) ? beta : tcol[j];
#pragma unroll
      for (int rr = 0; rr < QR_N; ++rr) {
        if (rr > j) {
          const float vtop = __shfl(tcol[rr], j) * scale;
          tcol[rr] -= tw * vtop;
        }
      }
      if (c >= j && c < QR_N) Rt[c][j] = rcol[j];
    }
  }
  __syncthreads();

  // ---- Phase 4: per-row solve y * R = A[t,:]; emit f16 [512][32] ----
  float rinv[QR_N];
#pragma unroll
  for (int cc = 0; cc < QR_N; ++cc) rinv[cc] = 1.0f / Rt[cc][cc];

  float y[QR_N];
#pragma unroll
  for (int cc = 0; cc < QR_N; ++cc) y[cc] = As[tid][cc];
#pragma unroll
  for (int cc = 0; cc < QR_N; ++cc) {
    float s = y[cc];
    int k = 0;
#pragma unroll
    for (; k + 1 < cc; k += 2) {
      const float2 rk = *reinterpret_cast<const float2*>(&Rt[cc][k]);
      s -= y[k] * rk.x + y[k + 1] * rk.y;
    }
    if (k < cc) s -= y[k] * Rt[cc][k];
    y[cc] = s * rinv[cc];
  }

  half8_t h0, h1, h2, h3;
#pragma unroll
  for (int e = 0; e < 8; ++e) h0[e] = (_Float16)y[e];
#pragma unroll
  for (int e = 0; e < 8; ++e) h1[e] = (_Float16)y[8 + e];
#pragma unroll
  for (int e = 0; e < 8; ++e) h2[e] = (_Float16)y[16 + e];
  h3[0] = (_Float16)y[24]; h3[1] = (_Float16)y[25];
#pragma unroll
  for (int e = 2; e < 8; ++e) h3[e] = (_Float16)0.0f;
  half8_t* qrow = reinterpret_cast<half8_t*>(qf + (size_t)tid * 32);
  qrow[0] = h0; qrow[1] = h1; qrow[2] = h2; qrow[3] = h3;
}

// ---------------------------------------------------------------------------
// Kernel 2 (R16-proven): MFMA matmul + LDS-transposed epilogue + NON-TEMPORAL
// output stores (out is write-once-never-read; nt stops L2 retention,
// protecting the x read stream -> -12.2 us measured in R16).
// ---------------------------------------------------------------------------
__global__ __launch_bounds__(256, 4) void dir_matmul(const float* __restrict__ x,
                                                     const _Float16* __restrict__ qf,
                                                     float* __restrict__ out,
                                                     int nblk32) {
  const int tid   = threadIdx.x;
  const int wid   = tid >> 6;
  const int l     = tid & 63;
  const int rloc  = l & 15;
  const int grp   = l >> 4;
  const int k0    = grp * 8;
  const int rhalf = (wid >> 1) * 16;
  const int chalf = (wid & 1) * 256;
  const int t2b   = (wid & 1) * 16;

  __shared__ float tile[4][16 * 132];
  float* tw = tile[wid];

  half8_t bq[16];
#pragma unroll
  for (int t2 = 0; t2 < 16; ++t2)
    bq[t2] = *reinterpret_cast<const half8_t*>(
        qf + (size_t)((t2b + t2) * 16 + rloc) * 32 + k0);

  for (int rb = blockIdx.x; rb < nblk32; rb += gridDim.x) {
    const int row = rb * 32 + rhalf + rloc;
    half8_t av;
    const float* xp = x + (size_t)row * QR_N + k0;
    if (grp < 3) {
#pragma unroll
      for (int e = 0; e < 4; ++e) {
        float2 v = *reinterpret_cast<const float2*>(xp + 2 * e);
        av[2 * e]     = (_Float16)v.x;
        av[2 * e + 1] = (_Float16)v.y;
      }
    } else {
      float2 v = *reinterpret_cast<const float2*>(xp);
      av[0] = (_Float16)v.x; av[1] = (_Float16)v.y;
#pragma unroll
      for (int e = 2; e < 8; ++e) av[e] = (_Float16)0.0f;
    }

#pragma unroll
    for (int cc = 0; cc < 2; ++cc) {
#pragma unroll
      for (int tt = 0; tt < 8; ++tt) {
        f32x4 acc = {0.0f, 0.0f, 0.0f, 0.0f};
        acc = __builtin_amdgcn_mfma_f32_16x16x32_f16(av, bq[cc * 8 + tt], acc, 0, 0, 0);
#pragma unroll
        for (int j = 0; j < 4; ++j)
          tw[(grp * 4 + j) * 132 + tt * 16 + rloc] = acc[j];
      }
      __syncthreads();
#pragma unroll
      for (int it = 0; it < 8; ++it) {
        const int r  = it * 2 + (l >> 5);
        const int cg = l & 31;
        f32x4 v = *reinterpret_cast<const f32x4*>(&tw[r * 132 + 4 * cg]);
        __builtin_nontemporal_store(
            v, reinterpret_cast<f32x4*>(
                   out + (size_t)(rb * 32 + rhalf + r) * OUTC + chalf + cc * 128 + 4 * cg));
      }
      __syncthreads();
    }
  }
}

extern "C" void kernel_launch(void* const* d_in, const int* in_sizes, int n_in,
                              void* d_out, int out_size, void* d_ws, size_t ws_size,
                              hipStream_t stream) {
  const float* input  = (const float*)d_in[0];   // [B, 26] f32
  const float* weight = (const float*)d_in[1];   // [512, 26] f32
  float* out = (float*)d_out;                    // [B, 512] f32
  _Float16* qf = (_Float16*)d_ws;                // [512][32] f16 scratch (32 KB)

  const int B = in_sizes[0] / QR_N;              // 262144
  const int nblk32 = B / 32;                     // 8192

  qr_kernel<<<1, 512, 0, stream>>>(weight, qf);
  dir_matmul<<<2048, 256, 0, stream>>>(input, qf, out, nblk32);
}